// Round 1
// baseline (842.942 us; speedup 1.0000x reference)
//
#include <hip/hip_runtime.h>
#include <stdint.h>

// ParallelFcWithAttention: B=16384, F=10, D=512, H=8, DH=64
// Plan: pack weights -> fused P+QKV+attention (per-head MFMA GEMM) -> Wo GEMM + LN + sum.
// All GEMMs on v_mfma_f32_16x16x32_bf16; A/B frags: lane holds [row=lane&15][k=(lane>>4)*8+j],
// C/D: row=(lane>>4)*4+r, col=lane&15 (learn_hip m89-verified mapping).

typedef __bf16 bf16;
typedef __bf16 bf16x8 __attribute__((ext_vector_type(8)));
typedef float f32x4 __attribute__((ext_vector_type(4)));

#define EPS 1e-5f

static constexpr size_t O_ELEMS   = (size_t)16384 * 10 * 512;   // 83,886,080
static constexpr size_t O_BYTES   = O_ELEMS * 2;                // 167,772,160
static constexpr size_t WQKV_ELEMS = (size_t)8 * 192 * 512;     // 786,432
static constexpr size_t WQKV_BYTES = WQKV_ELEMS * 2;

__device__ __forceinline__ void async_copy16(void* lds, const void* g) {
  // wave-uniform LDS base; HW scatters lane i at base + i*16
  __builtin_amdgcn_global_load_lds(
      (const __attribute__((address_space(1))) uint32_t*)g,
      (__attribute__((address_space(3))) uint32_t*)lds, 16, 0, 0);
}

// ---------------- pack weights to bf16 ----------------
// wqkv layout: [h][0:64 = Wq rows h*64.., 64:128 = Wk, 128:192 = Wv][512]
__global__ __launch_bounds__(256) void pack_weights(
    const float* __restrict__ Wq, const float* __restrict__ Wk,
    const float* __restrict__ Wv, const float* __restrict__ Wo,
    bf16* __restrict__ wqkv, bf16* __restrict__ wob) {
  int idx = blockIdx.x * 256 + threadIdx.x;
#pragma unroll
  for (int u = 0; u < 4; ++u) {
    int i = idx + u * 262144;
    if (i < 786432) {
      int pr = i >> 9, k = i & 511;
      int h = pr / 192, w = pr - h * 192;
      int t = w >> 6, r = w & 63;
      const float* src = (t == 0) ? Wq : ((t == 1) ? Wk : Wv);
      wqkv[i] = (bf16)src[(h * 64 + r) * 512 + k];
    } else {
      int j = i - 786432;
      wob[j] = (bf16)Wo[j];
    }
  }
}

// ---------------- fused P + QKV GEMM + attention ----------------
// Workgroup: 4 batch elems -> 40 real rows, padded to 48 (3 M-tiles).
// LDS: sA = P tile [8 slabs][48 rows][8 chunks*16B], XOR-swizzled (chunk' = chunk ^ (row&7)).
//      sU = union { B slab [192 rows][8 chunks] (24576 B) | qkv[48][200] bf16 + sc[4][10][12] f32 }.
__global__ __launch_bounds__(256, 2) void kern_attn(
    const float* __restrict__ x, const float* __restrict__ Wf,
    const float* __restrict__ bfv, const bf16* __restrict__ wqkv,
    const float* __restrict__ bq, const float* __restrict__ bk,
    const float* __restrict__ bv, bf16* __restrict__ O) {
  __shared__ __align__(16) char sA[8 * 48 * 128];   // 49152
  __shared__ __align__(16) char sU[24576];
  bf16* qkv = (bf16*)sU;                 // [48][200], cols 0-63 q, 64-127 k, 128-191 v
  float* sc = (float*)(sU + 19200);      // [4][10][12]

  const int tid = threadIdx.x;
  const int wave = tid >> 6;
  const int lane = tid & 63;
  const int lm = lane & 15;
  const int lg = lane >> 4;
  const int b0 = blockIdx.x * 4;

  // ---- compute P = relu(x*Wf + bf) into sA (rows >=40 zeroed) ----
#pragma unroll
  for (int it = 0; it < 12; ++it) {
    int c = tid + it * 256;            // chunk id: c = s*384 + r*8 + kc'
    int s = c / 384, rem = c - s * 384;
    int r = rem >> 3, kcp = rem & 7;
    int kc = kcp ^ (r & 7);
    int k = s * 64 + kc * 8;
    bf16x8 pv;
    if (r < 40) {
      int bl = r / 10, f = r - bl * 10;
      float xv = x[(b0 + bl) * 10 + f];
      const float* wf = Wf + f * 512 + k;
      const float* bp = bfv + f * 512 + k;
#pragma unroll
      for (int j = 0; j < 8; ++j) {
        float p = fmaxf(xv * wf[j] + bp[j], 0.f);
        pv[j] = (bf16)p;
      }
    } else {
#pragma unroll
      for (int j = 0; j < 8; ++j) pv[j] = (bf16)0.f;
    }
    *(bf16x8*)(sA + s * 6144 + r * 128 + kcp * 16) = pv;
  }

  const int lr = lane >> 3;
  const int kcp2 = lane & 7;
  const int kcg = kcp2 ^ lr;           // swizzled global chunk for staging

  for (int h = 0; h < 8; ++h) {
    f32x4 acc[3][3];
#pragma unroll
    for (int i = 0; i < 3; ++i)
#pragma unroll
      for (int j = 0; j < 3; ++j) { f32x4 z = {0.f, 0.f, 0.f, 0.f}; acc[i][j] = z; }

    const bf16* wh = wqkv + (size_t)h * 192 * 512;

    for (int s = 0; s < 8; ++s) {
      // stage B slab (192 rows x 64 k): 24 rowblocks of 8 rows, 6 per wave
#pragma unroll
      for (int jb = 0; jb < 6; ++jb) {
        int rb = wave + 4 * jb;
        int rr = rb * 8 + lr;
        async_copy16(sU + rb * 1024, wh + (size_t)rr * 512 + s * 64 + kcg * 8);
      }
      __syncthreads();
#pragma unroll
      for (int kk = 0; kk < 2; ++kk) {
        int kcl = kk * 4 + lg;
        bf16x8 af[3], bfr[3];
#pragma unroll
        for (int mt = 0; mt < 3; ++mt) {
          int m = mt * 16 + lm;
          af[mt] = *(const bf16x8*)(sA + s * 6144 + m * 128 + ((kcl ^ (m & 7)) << 4));
        }
#pragma unroll
        for (int nt = 0; nt < 3; ++nt) {
          int n = wave * 48 + nt * 16 + lm;
          bfr[nt] = *(const bf16x8*)(sU + n * 128 + ((kcl ^ (n & 7)) << 4));
        }
#pragma unroll
        for (int mt = 0; mt < 3; ++mt)
#pragma unroll
          for (int nt = 0; nt < 3; ++nt)
            acc[mt][nt] = __builtin_amdgcn_mfma_f32_16x16x32_bf16(af[mt], bfr[nt], acc[mt][nt], 0, 0, 0);
      }
      __syncthreads();
    }

    // spill q/k/v (+bias) to LDS; B slab is dead after the barrier above
#pragma unroll
    for (int nt = 0; nt < 3; ++nt) {
      int col = wave * 48 + nt * 16 + lm;
      float bias;
      if (col < 64) bias = bq[h * 64 + col];
      else if (col < 128) bias = bk[h * 64 + col - 64];
      else bias = bv[h * 64 + col - 128];
#pragma unroll
      for (int mt = 0; mt < 3; ++mt)
#pragma unroll
        for (int r = 0; r < 4; ++r) {
          int row = mt * 16 + lg * 4 + r;
          if (row < 40) qkv[row * 200 + col] = (bf16)(acc[mt][nt][r] + bias);
        }
    }
    __syncthreads();

    // scores: one wave per batch elem; lane covers (i,j) pairs p and p+64
    {
      int b = wave;
#pragma unroll
      for (int pp = 0; pp < 2; ++pp) {
        int p = lane + pp * 64;
        if (p < 100) {
          int i = p / 10, j = p - i * 10;
          const bf16x8* qr = (const bf16x8*)(qkv + (b * 10 + i) * 200);
          const bf16x8* kr = (const bf16x8*)(qkv + (b * 10 + j) * 200 + 64);
          float d = 0.f;
#pragma unroll
          for (int c8 = 0; c8 < 8; ++c8) {
            bf16x8 qv = qr[c8], kv = kr[c8];
#pragma unroll
            for (int e = 0; e < 8; ++e) d += (float)qv[e] * (float)kv[e];
          }
          sc[(b * 10 + i) * 12 + j] = d * 0.125f;   // 1/sqrt(64)
        }
      }
    }
    __syncthreads();

    // softmax over j (rows of sc), one thread per (b,i)
    if (tid < 40) {
      float* row = sc + tid * 12;
      float m = row[0];
#pragma unroll
      for (int j = 1; j < 10; ++j) m = fmaxf(m, row[j]);
      float e[10], sum = 0.f;
#pragma unroll
      for (int j = 0; j < 10; ++j) { e[j] = __expf(row[j] - m); sum += e[j]; }
      float inv = 1.f / sum;
#pragma unroll
      for (int j = 0; j < 10; ++j) row[j] = e[j] * inv;
    }
    __syncthreads();

    // o = attn @ v, write to O[(b,f), h*64+d] bf16
#pragma unroll
    for (int u = 0; u < 10; ++u) {
      int id = tid + u * 256;           // 2560 outputs: 4b x 10i x 64d
      int b = id / 640, rem2 = id - b * 640;
      int i = rem2 >> 6, d = rem2 & 63;
      const float* ar = sc + (b * 10 + i) * 12;
      float o = 0.f;
#pragma unroll
      for (int j = 0; j < 10; ++j)
        o += ar[j] * (float)qkv[(b * 10 + j) * 200 + 128 + d];
      O[((size_t)(b0 + b) * 10 + i) * 512 + h * 64 + d] = (bf16)o;
    }
    __syncthreads();  // protect union before next head's staging
  }
}

// ---------------- O @ Wo.T + bo -> LayerNorm -> sum over F ----------------
// Workgroup: 4 batch elems (40 rows + 8 pad), full N=512 so LN sees whole rows.
__global__ __launch_bounds__(256, 2) void kern_out(
    const bf16* __restrict__ O, const bf16* __restrict__ wob,
    const float* __restrict__ bo, const float* __restrict__ gamma,
    const float* __restrict__ beta, float* __restrict__ out) {
  __shared__ __align__(16) char sAB[71680];  // A slab @0 (6144) | B slab @6144 (65536); epilogue: ln bf16 [48][520]
  __shared__ float partial[48][4][2];
  __shared__ float stats[48][2];
  char* As = sAB;
  char* Bs = sAB + 6144;
  bf16* lnb = (bf16*)sAB;

  const int tid = threadIdx.x;
  const int wave = tid >> 6, lane = tid & 63;
  const int lm = lane & 15, lg = lane >> 4;
  const int m0 = blockIdx.x * 40;

  f32x4 acc[3][8];
#pragma unroll
  for (int i = 0; i < 3; ++i)
#pragma unroll
    for (int j = 0; j < 8; ++j) { f32x4 z = {0.f, 0.f, 0.f, 0.f}; acc[i][j] = z; }

  const int lr = lane >> 3;
  const int kcp2 = lane & 7;
  const int kcg = kcp2 ^ lr;

  for (int s = 0; s < 8; ++s) {
    {  // stage A: 6 rowblocks (48 rows), clamp pad rows to row 39
      int rr = wave * 8 + lr;
      int rm = min(rr, 39);
      async_copy16(As + wave * 1024, O + (size_t)(m0 + rm) * 512 + s * 64 + kcg * 8);
      if (wave < 2) {
        int rr2 = (4 + wave) * 8 + lr;
        int rm2 = min(rr2, 39);
        async_copy16(As + (4 + wave) * 1024, O + (size_t)(m0 + rm2) * 512 + s * 64 + kcg * 8);
      }
    }
    // stage B: Wo slab, 64 rowblocks, 16 per wave
#pragma unroll
    for (int jb = 0; jb < 16; ++jb) {
      int rb = wave + 4 * jb;
      int n = rb * 8 + lr;
      async_copy16(Bs + rb * 1024, wob + (size_t)n * 512 + s * 64 + kcg * 8);
    }
    __syncthreads();
#pragma unroll
    for (int kk = 0; kk < 2; ++kk) {
      int kcl = kk * 4 + lg;
      bf16x8 af[3], bfr[8];
#pragma unroll
      for (int mt = 0; mt < 3; ++mt) {
        int m = mt * 16 + lm;
        af[mt] = *(const bf16x8*)(As + m * 128 + ((kcl ^ (m & 7)) << 4));
      }
#pragma unroll
      for (int nt = 0; nt < 8; ++nt) {
        int n = wave * 128 + nt * 16 + lm;
        bfr[nt] = *(const bf16x8*)(Bs + n * 128 + ((kcl ^ (n & 7)) << 4));
      }
#pragma unroll
      for (int mt = 0; mt < 3; ++mt)
#pragma unroll
        for (int nt = 0; nt < 8; ++nt)
          acc[mt][nt] = __builtin_amdgcn_mfma_f32_16x16x32_bf16(af[mt], bfr[nt], acc[mt][nt], 0, 0, 0);
    }
    __syncthreads();
  }

  // + bias
#pragma unroll
  for (int nt = 0; nt < 8; ++nt) {
    int col = wave * 128 + nt * 16 + lm;
    float bb = bo[col];
#pragma unroll
    for (int mt = 0; mt < 3; ++mt)
#pragma unroll
      for (int r = 0; r < 4; ++r) acc[mt][nt][r] += bb;
  }

  // per-row mean/var: lane-local over 8 nt, then xor-shuffle across the 16-lane col group
#pragma unroll
  for (int mt = 0; mt < 3; ++mt)
#pragma unroll
    for (int r = 0; r < 4; ++r) {
      float s1 = 0.f, s2 = 0.f;
#pragma unroll
      for (int nt = 0; nt < 8; ++nt) { float v = acc[mt][nt][r]; s1 += v; s2 += v * v; }
#pragma unroll
      for (int off = 1; off < 16; off <<= 1) {
        s1 += __shfl_xor(s1, off);
        s2 += __shfl_xor(s2, off);
      }
      if (lm == 0) {
        int row = mt * 16 + lg * 4 + r;
        partial[row][wave][0] = s1;
        partial[row][wave][1] = s2;
      }
    }
  __syncthreads();
  if (tid < 48) {
    float s1 = partial[tid][0][0] + partial[tid][1][0] + partial[tid][2][0] + partial[tid][3][0];
    float s2 = partial[tid][0][1] + partial[tid][1][1] + partial[tid][2][1] + partial[tid][3][1];
    float mu = s1 * (1.f / 512.f);
    float var = s2 * (1.f / 512.f) - mu * mu;
    stats[tid][0] = mu;
    stats[tid][1] = rsqrtf(var + EPS);
  }
  __syncthreads();
  // normalized values -> LDS bf16 (GEMM buffers dead now), stride 520 to break bank alias
#pragma unroll
  for (int mt = 0; mt < 3; ++mt)
#pragma unroll
    for (int r = 0; r < 4; ++r) {
      int row = mt * 16 + lg * 4 + r;
      float mu = stats[row][0], rr = stats[row][1];
#pragma unroll
      for (int nt = 0; nt < 8; ++nt) {
        int col = wave * 128 + nt * 16 + lm;
        lnb[row * 520 + col] = (bf16)((acc[mt][nt][r] - mu) * rr);
      }
    }
  __syncthreads();
  // out[b,n] = gamma[n]*sum_f lnv + 10*beta[n]
#pragma unroll
  for (int u = 0; u < 8; ++u) {
    int id = tid + u * 256;
    int b = id >> 9, n = id & 511;
    float ssum = 0.f;
#pragma unroll
    for (int f = 0; f < 10; ++f) ssum += (float)lnb[(b * 10 + f) * 520 + n];
    out[(size_t)(blockIdx.x * 4 + b) * 512 + n] = gamma[n] * ssum + 10.f * beta[n];
  }
}

extern "C" void kernel_launch(void* const* d_in, const int* in_sizes, int n_in,
                              void* d_out, int out_size, void* d_ws, size_t ws_size,
                              hipStream_t stream) {
  const float* x     = (const float*)d_in[0];
  const float* Wf    = (const float*)d_in[1];
  const float* bfv   = (const float*)d_in[2];
  const float* Wq    = (const float*)d_in[3];
  const float* Wk    = (const float*)d_in[4];
  const float* Wv    = (const float*)d_in[5];
  const float* bq    = (const float*)d_in[6];
  const float* bk    = (const float*)d_in[7];
  const float* bv    = (const float*)d_in[8];
  const float* Wo    = (const float*)d_in[9];
  const float* bo    = (const float*)d_in[10];
  const float* gamma = (const float*)d_in[11];
  const float* beta  = (const float*)d_in[12];
  float* out = (float*)d_out;

  char* ws = (char*)d_ws;
  bf16* O    = (bf16*)ws;                              // 167,772,160 B
  bf16* wqkv = (bf16*)(ws + O_BYTES);                  // 1,572,864 B
  bf16* wob  = (bf16*)(ws + O_BYTES + WQKV_BYTES);     // 524,288 B

  pack_weights<<<1024, 256, 0, stream>>>(Wq, Wk, Wv, Wo, wqkv, wob);
  kern_attn<<<4096, 256, 0, stream>>>(x, Wf, bfv, wqkv, bq, bk, bv, O);
  kern_out<<<4096, 256, 0, stream>>>(O, wob, bo, gamma, beta, out);
}